// Round 1
// baseline (439.252 us; speedup 1.0000x reference)
//
#include <hip/hip_runtime.h>
#include <math.h>

#define B 8
#define C 32
#define H 384
#define W 384
#define HW (H*W)

#define TW 32
#define TH 8

__device__ __forceinline__ float reflect_coord(float coord, int size) {
    // torch grid_sample reflection, align_corners=False: reflect over [-0.5, size-0.5]
    float span = (float)size;
    float xr = fabsf(coord + 0.5f);
    float extra = fmodf(xr, span);
    float flips = floorf(xr / span);
    float out = (fmodf(flips, 2.0f) == 0.0f) ? (extra - 0.5f) : (span - extra - 0.5f);
    return fminf(fmaxf(out, 0.0f), (float)(size - 1));
}

// One thread per (b,h,w): 3x3 conv over 32 channels -> 2 offsets -> tanh ->
// final reflected absolute sample coords (ix, iy) written to workspace.
__global__ void offset_kernel(const float* __restrict__ x,
                              const float* __restrict__ ow,
                              const float* __restrict__ ob,
                              float* __restrict__ ws_ix,
                              float* __restrict__ ws_iy) {
    __shared__ float w_lds[2 * C * 9];
    int tid = threadIdx.x;
    for (int i = tid; i < 2 * C * 9; i += 256) w_lds[i] = ow[i];
    __syncthreads();

    int gid = blockIdx.x * 256 + tid;            // b*HW + h*W + w
    int w_ = gid % W;
    int h_ = (gid / W) % H;
    int b_ = gid / HW;

    const float* xb = x + (size_t)b_ * C * HW;
    float acc0 = ob[0];
    float acc1 = ob[1];
    for (int c = 0; c < C; ++c) {
        const float* xc = xb + c * HW;
        #pragma unroll
        for (int ky = 0; ky < 3; ++ky) {
            int hy = h_ + ky - 1;
            if (hy < 0 || hy >= H) continue;     // zero pad
            const float* xrow = xc + hy * W;
            #pragma unroll
            for (int kx = 0; kx < 3; ++kx) {
                int wx = w_ + kx - 1;
                if (wx < 0 || wx >= W) continue; // zero pad
                float v = xrow[wx];
                acc0 = fmaf(v, w_lds[(0 * C + c) * 9 + ky * 3 + kx], acc0);
                acc1 = fmaf(v, w_lds[(1 * C + c) * 9 + ky * 3 + kx], acc1);
            }
        }
    }
    float off0 = tanhf(acc0);   // MAX_OFFSET = 1.0
    float off1 = tanhf(acc1);

    float fx = (float)w_ + off0;
    float fy = (float)h_ + off1;
    float gx = 2.0f * fx / (float)(W - 1) - 1.0f;
    float gy = 2.0f * fy / (float)(H - 1) - 1.0f;
    float ix = ((gx + 1.0f) * (float)W - 1.0f) * 0.5f;
    float iy = ((gy + 1.0f) * (float)H - 1.0f) * 0.5f;
    ws_ix[gid] = reflect_coord(ix, W);
    ws_iy[gid] = reflect_coord(iy, H);
}

// Block = one (b,c), 32x8 output tile. Stage bilinear-sampled x_def tile
// (10x34) in LDS, then 3x3 depthwise conv + ReLU.
__global__ void sample_dw_kernel(const float* __restrict__ x,
                                 const float* __restrict__ ws_ix,
                                 const float* __restrict__ ws_iy,
                                 const float* __restrict__ dww,
                                 float* __restrict__ out) {
    __shared__ float xd[(TH + 2) * (TW + 2)];   // 10 * 34 = 340

    int bc = blockIdx.z;                        // b*C + c
    int b_ = bc / C;
    int c_ = bc % C;
    int h0 = blockIdx.y * TH;
    int w0 = blockIdx.x * TW;
    int tid = threadIdx.x;

    const float* xc  = x + ((size_t)b_ * C + c_) * HW;
    const float* ixp = ws_ix + (size_t)b_ * HW;
    const float* iyp = ws_iy + (size_t)b_ * HW;

    for (int i = tid; i < (TH + 2) * (TW + 2); i += 256) {
        int r = i / (TW + 2);
        int q = i % (TW + 2);
        int hp = h0 - 1 + r;
        int wp = w0 - 1 + q;
        float v = 0.0f;                          // dw-conv zero pad
        if (hp >= 0 && hp < H && wp >= 0 && wp < W) {
            int p = hp * W + wp;
            float ix = ixp[p];
            float iy = iyp[p];
            float ix0f = floorf(ix), iy0f = floorf(iy);
            float wx1 = ix - ix0f, wy1 = iy - iy0f;
            float wx0 = 1.0f - wx1, wy0 = 1.0f - wy1;
            int ix0 = min(max((int)ix0f, 0), W - 1);
            int iy0 = min(max((int)iy0f, 0), H - 1);
            int ix1 = min(ix0 + 1, W - 1);
            int iy1 = min(iy0 + 1, H - 1);
            float v00 = xc[iy0 * W + ix0];
            float v01 = xc[iy0 * W + ix1];
            float v10 = xc[iy1 * W + ix0];
            float v11 = xc[iy1 * W + ix1];
            v = (v00 * wx0 + v01 * wx1) * wy0 + (v10 * wx0 + v11 * wx1) * wy1;
        }
        xd[i] = v;
    }

    float wk[9];
    const float* wc = dww + c_ * 9;
    #pragma unroll
    for (int i = 0; i < 9; ++i) wk[i] = wc[i];

    __syncthreads();

    int tx = tid % TW;
    int ty = tid / TW;
    float acc = 0.0f;
    #pragma unroll
    for (int ky = 0; ky < 3; ++ky) {
        #pragma unroll
        for (int kx = 0; kx < 3; ++kx) {
            acc = fmaf(xd[(ty + ky) * (TW + 2) + tx + kx], wk[ky * 3 + kx], acc);
        }
    }
    acc = fmaxf(acc, 0.0f);
    out[((size_t)b_ * C + c_) * HW + (size_t)(h0 + ty) * W + (w0 + tx)] = acc;
}

extern "C" void kernel_launch(void* const* d_in, const int* in_sizes, int n_in,
                              void* d_out, int out_size, void* d_ws, size_t ws_size,
                              hipStream_t stream) {
    const float* x   = (const float*)d_in[0];
    const float* ow  = (const float*)d_in[1];
    const float* ob  = (const float*)d_in[2];
    const float* dww = (const float*)d_in[3];
    float* out = (float*)d_out;

    float* ws_ix = (float*)d_ws;
    float* ws_iy = ws_ix + (size_t)B * HW;

    dim3 g1((B * HW) / 256);
    offset_kernel<<<g1, 256, 0, stream>>>(x, ow, ob, ws_ix, ws_iy);

    dim3 g2(W / TW, H / TH, B * C);
    sample_dw_kernel<<<g2, 256, 0, stream>>>(x, ws_ix, ws_iy, dww, out);
}

// Round 2
// 218.751 us; speedup vs baseline: 2.0080x; 2.0080x over previous
//
#include <hip/hip_runtime.h>
#include <math.h>

#define B 8
#define C 32
#define H 384
#define W 384
#define HW (H*W)

// ---------------- offset kernel tiling ----------------
#define K1_TW 64
#define K1_TH 16
#define K1_PW 66                 // K1_TW+2 valid cols
#define K1_PH 18                 // K1_TH+2 rows
#define K1_STRIDE 68             // padded (even) LDS row stride
#define K1_ELEMS (K1_PH * K1_PW) // 1188

__device__ __forceinline__ float reflect_coord(float coord, int size) {
    // torch grid_sample reflection, align_corners=False: reflect over [-0.5, size-0.5]
    float span = (float)size;
    float xr = fabsf(coord + 0.5f);
    float extra = fmodf(xr, span);
    float flips = floorf(xr / span);
    float out = (fmodf(flips, 2.0f) == 0.0f) ? (extra - 0.5f) : (span - extra - 0.5f);
    return fminf(fmaxf(out, 0.0f), (float)(size - 1));
}

// Tiled 3x3 conv (32ch -> 2) + tanh + coord math. Each block: 64x16 output
// tile; each thread: 2 cols x 2 rows. Channel loop with double-buffered LDS.
__global__ __launch_bounds__(256) void offset_kernel(
        const float* __restrict__ x,
        const float* __restrict__ ow,
        const float* __restrict__ ob,
        float2* __restrict__ ws) {
    __shared__ float xs[2][K1_PH * K1_STRIDE];

    const int tid = threadIdx.x;
    const int b_ = blockIdx.z;
    const int h0 = blockIdx.y * K1_TH;
    const int w0 = blockIdx.x * K1_TW;
    const float* xb = x + (size_t)b_ * C * HW;

    const int tx2 = (tid & 31) * 2;        // output cols tx2, tx2+1
    const int ty0 = (tid >> 5) * 2;        // output rows ty0, ty0+1

    float stg[5];

#define K1_LOAD_STAGE(cc) do {                                              \
        const float* xc_ = xb + (cc) * HW;                                  \
        _Pragma("unroll")                                                   \
        for (int k = 0; k < 5; ++k) {                                       \
            int i = tid + k * 256;                                          \
            float v = 0.0f;                                                 \
            if (i < K1_ELEMS) {                                             \
                int r = i / K1_PW, q = i - r * K1_PW;                       \
                int hp = h0 - 1 + r, wp = w0 - 1 + q;                       \
                if (hp >= 0 && hp < H && wp >= 0 && wp < W)                 \
                    v = xc_[hp * W + wp];                                   \
            }                                                               \
            stg[k] = v;                                                     \
        }                                                                   \
    } while (0)

#define K1_WRITE_STAGE(bufi) do {                                           \
        float* dst_ = xs[bufi];                                             \
        _Pragma("unroll")                                                   \
        for (int k = 0; k < 5; ++k) {                                       \
            int i = tid + k * 256;                                          \
            if (i < K1_ELEMS) {                                             \
                int r = i / K1_PW, q = i - r * K1_PW;                       \
                dst_[r * K1_STRIDE + q] = stg[k];                           \
            }                                                               \
        }                                                                   \
    } while (0)

    K1_LOAD_STAGE(0);
    K1_WRITE_STAGE(0);
    __syncthreads();

    float acc[2][2][2];   // [filter][row j][col]
    {
        float b0 = ob[0], b1 = ob[1];
        #pragma unroll
        for (int j = 0; j < 2; ++j)
            #pragma unroll
            for (int q = 0; q < 2; ++q) { acc[0][j][q] = b0; acc[1][j][q] = b1; }
    }

    for (int c = 0; c < C; ++c) {
        if (c + 1 < C) K1_LOAD_STAGE(c + 1);

        // wave-uniform weight loads -> scalar pipe
        const float* wap = ow + c * 9;
        const float* wbp = ow + (C + c) * 9;
        float wA[9], wB[9];
        #pragma unroll
        for (int k = 0; k < 9; ++k) { wA[k] = wap[k]; wB[k] = wbp[k]; }

        const float* buf = xs[c & 1];
        #pragma unroll
        for (int r = 0; r < 4; ++r) {
            const float* rowp = buf + (ty0 + r) * K1_STRIDE + tx2;
            float2 p0 = *(const float2*)rowp;
            float2 p1 = *(const float2*)(rowp + 2);
            #pragma unroll
            for (int ky = 0; ky < 3; ++ky) {
                int j = r - ky;
                if (j < 0 || j > 1) continue;
                acc[0][j][0] = fmaf(p0.x, wA[ky*3+0], fmaf(p0.y, wA[ky*3+1], fmaf(p1.x, wA[ky*3+2], acc[0][j][0])));
                acc[0][j][1] = fmaf(p0.y, wA[ky*3+0], fmaf(p1.x, wA[ky*3+1], fmaf(p1.y, wA[ky*3+2], acc[0][j][1])));
                acc[1][j][0] = fmaf(p0.x, wB[ky*3+0], fmaf(p0.y, wB[ky*3+1], fmaf(p1.x, wB[ky*3+2], acc[1][j][0])));
                acc[1][j][1] = fmaf(p0.y, wB[ky*3+0], fmaf(p1.x, wB[ky*3+1], fmaf(p1.y, wB[ky*3+2], acc[1][j][1])));
            }
        }

        if (c + 1 < C) K1_WRITE_STAGE((c + 1) & 1);
        __syncthreads();
    }

    // tanh -> abs coords -> reflect -> store interleaved (ix,iy) pairs
    #pragma unroll
    for (int j = 0; j < 2; ++j) {
        int hh = h0 + ty0 + j;
        float4 o;
        #pragma unroll
        for (int q = 0; q < 2; ++q) {
            int wwp = w0 + tx2 + q;
            float off0 = tanhf(acc[0][j][q]);
            float off1 = tanhf(acc[1][j][q]);
            float fx = (float)wwp + off0;
            float fy = (float)hh + off1;
            float gx = 2.0f * fx / (float)(W - 1) - 1.0f;
            float gy = 2.0f * fy / (float)(H - 1) - 1.0f;
            float ix = ((gx + 1.0f) * (float)W - 1.0f) * 0.5f;
            float iy = ((gy + 1.0f) * (float)H - 1.0f) * 0.5f;
            float ixr = reflect_coord(ix, W);
            float iyr = reflect_coord(iy, H);
            if (q == 0) { o.x = ixr; o.y = iyr; }
            else        { o.z = ixr; o.w = iyr; }
        }
        *(float4*)&ws[(size_t)b_ * HW + (size_t)hh * W + (w0 + tx2)] = o;
    }
}

// ---------------- sample + depthwise conv kernel ----------------
#define K2_TW 64
#define K2_TH 8
#define K2_PW 66
#define K2_PH 10
#define K2_STRIDE 68
#define K2_ELEMS (K2_PH * K2_PW)   // 660

__global__ __launch_bounds__(256) void sample_dw_kernel(
        const float* __restrict__ x,
        const float2* __restrict__ ws,
        const float* __restrict__ dww,
        float* __restrict__ out) {
    __shared__ float xd[K2_PH * K2_STRIDE];

    const int bc = blockIdx.z;           // b*C + c
    const int b_ = bc / C;
    const int c_ = bc % C;
    const int h0 = blockIdx.y * K2_TH;
    const int w0 = blockIdx.x * K2_TW;
    const int tid = threadIdx.x;

    const float* xc = x + ((size_t)b_ * C + c_) * HW;
    const float2* wsb = ws + (size_t)b_ * HW;

    #pragma unroll
    for (int k = 0; k < 3; ++k) {
        int i = tid + k * 256;
        if (i >= K2_ELEMS) break;
        int r = i / K2_PW, q = i - r * K2_PW;
        int hp = h0 - 1 + r;
        int wp = w0 - 1 + q;
        float v = 0.0f;                   // dw-conv zero pad
        if (hp >= 0 && hp < H && wp >= 0 && wp < W) {
            float2 crd = wsb[hp * W + wp];
            float ix = crd.x, iy = crd.y;
            float ix0f = floorf(ix), iy0f = floorf(iy);
            float wx1 = ix - ix0f, wy1 = iy - iy0f;
            float wx0 = 1.0f - wx1, wy0 = 1.0f - wy1;
            int ix0 = min(max((int)ix0f, 0), W - 1);
            int iy0 = min(max((int)iy0f, 0), H - 1);
            int ix1 = min(ix0 + 1, W - 1);
            int iy1 = min(iy0 + 1, H - 1);
            float v00 = xc[iy0 * W + ix0];
            float v01 = xc[iy0 * W + ix1];
            float v10 = xc[iy1 * W + ix0];
            float v11 = xc[iy1 * W + ix1];
            v = (v00 * wx0 + v01 * wx1) * wy0 + (v10 * wx0 + v11 * wx1) * wy1;
        }
        xd[r * K2_STRIDE + q] = v;
    }

    // wave-uniform -> scalar loads
    float wk[9];
    const float* wc = dww + c_ * 9;
    #pragma unroll
    for (int i = 0; i < 9; ++i) wk[i] = wc[i];

    __syncthreads();

    const int tx2 = (tid & 31) * 2;
    const int ty  = tid >> 5;
    float a0 = 0.0f, a1 = 0.0f;
    #pragma unroll
    for (int ky = 0; ky < 3; ++ky) {
        const float* rowp = xd + (ty + ky) * K2_STRIDE + tx2;
        float2 p0 = *(const float2*)rowp;
        float2 p1 = *(const float2*)(rowp + 2);
        a0 = fmaf(p0.x, wk[ky*3+0], fmaf(p0.y, wk[ky*3+1], fmaf(p1.x, wk[ky*3+2], a0)));
        a1 = fmaf(p0.y, wk[ky*3+0], fmaf(p1.x, wk[ky*3+1], fmaf(p1.y, wk[ky*3+2], a1)));
    }
    float2 res;
    res.x = fmaxf(a0, 0.0f);
    res.y = fmaxf(a1, 0.0f);
    *(float2*)&out[((size_t)b_ * C + c_) * HW + (size_t)(h0 + ty) * W + (w0 + tx2)] = res;
}

extern "C" void kernel_launch(void* const* d_in, const int* in_sizes, int n_in,
                              void* d_out, int out_size, void* d_ws, size_t ws_size,
                              hipStream_t stream) {
    const float* x   = (const float*)d_in[0];
    const float* ow  = (const float*)d_in[1];
    const float* ob  = (const float*)d_in[2];
    const float* dww = (const float*)d_in[3];
    float* out = (float*)d_out;
    float2* ws = (float2*)d_ws;

    dim3 g1(W / K1_TW, H / K1_TH, B);
    offset_kernel<<<g1, 256, 0, stream>>>(x, ow, ob, ws);

    dim3 g2(W / K2_TW, H / K2_TH, B * C);
    sample_dw_kernel<<<g2, 256, 0, stream>>>(x, ws, dww, out);
}

// Round 4
// 135.866 us; speedup vs baseline: 3.2330x; 1.6101x over previous
//
#include <hip/hip_runtime.h>
#include <math.h>

#define B 8
#define C 32
#define H 384
#define W 384
#define HW (H*W)

// ---------------- offset kernel tiling ----------------
#define K1_TW 64
#define K1_TH 16
#define K1_PW 66
#define K1_PH 18
#define K1_STRIDE 68
#define K1_ELEMS (K1_PH * K1_PW)

__device__ __forceinline__ float reflect_coord(float coord, int size) {
    float span = (float)size;
    float xr = fabsf(coord + 0.5f);
    float extra = fmodf(xr, span);
    float flips = floorf(xr / span);
    float out = (fmodf(flips, 2.0f) == 0.0f) ? (extra - 0.5f) : (span - extra - 0.5f);
    return fminf(fmaxf(out, 0.0f), (float)(size - 1));
}

__global__ __launch_bounds__(256) void offset_kernel(
        const float* __restrict__ x,
        const float* __restrict__ ow,
        const float* __restrict__ ob,
        float2* __restrict__ ws) {
    __shared__ float xs[2][K1_PH * K1_STRIDE];

    const int tid = threadIdx.x;
    const int b_ = blockIdx.z;
    const int h0 = blockIdx.y * K1_TH;
    const int w0 = blockIdx.x * K1_TW;
    const float* xb = x + (size_t)b_ * C * HW;

    const int tx2 = (tid & 31) * 2;
    const int ty0 = (tid >> 5) * 2;

    float stg[5];

#define K1_LOAD_STAGE(cc) do {                                              \
        const float* xc_ = xb + (cc) * HW;                                  \
        _Pragma("unroll")                                                   \
        for (int k = 0; k < 5; ++k) {                                       \
            int i = tid + k * 256;                                          \
            float v = 0.0f;                                                 \
            if (i < K1_ELEMS) {                                             \
                int r = i / K1_PW, q = i - r * K1_PW;                       \
                int hp = h0 - 1 + r, wp = w0 - 1 + q;                       \
                if (hp >= 0 && hp < H && wp >= 0 && wp < W)                 \
                    v = xc_[hp * W + wp];                                   \
            }                                                               \
            stg[k] = v;                                                     \
        }                                                                   \
    } while (0)

#define K1_WRITE_STAGE(bufi) do {                                           \
        float* dst_ = xs[bufi];                                             \
        _Pragma("unroll")                                                   \
        for (int k = 0; k < 5; ++k) {                                       \
            int i = tid + k * 256;                                          \
            if (i < K1_ELEMS) {                                             \
                int r = i / K1_PW, q = i - r * K1_PW;                       \
                dst_[r * K1_STRIDE + q] = stg[k];                           \
            }                                                               \
        }                                                                   \
    } while (0)

    K1_LOAD_STAGE(0);
    K1_WRITE_STAGE(0);
    __syncthreads();

    float acc[2][2][2];
    {
        float b0 = ob[0], b1 = ob[1];
        #pragma unroll
        for (int j = 0; j < 2; ++j)
            #pragma unroll
            for (int q = 0; q < 2; ++q) { acc[0][j][q] = b0; acc[1][j][q] = b1; }
    }

    for (int c = 0; c < C; ++c) {
        if (c + 1 < C) K1_LOAD_STAGE(c + 1);

        const float* wap = ow + c * 9;
        const float* wbp = ow + (C + c) * 9;
        float wA[9], wB[9];
        #pragma unroll
        for (int k = 0; k < 9; ++k) { wA[k] = wap[k]; wB[k] = wbp[k]; }

        const float* buf = xs[c & 1];
        #pragma unroll
        for (int r = 0; r < 4; ++r) {
            const float* rowp = buf + (ty0 + r) * K1_STRIDE + tx2;
            float2 p0 = *(const float2*)rowp;
            float2 p1 = *(const float2*)(rowp + 2);
            #pragma unroll
            for (int ky = 0; ky < 3; ++ky) {
                int j = r - ky;
                if (j < 0 || j > 1) continue;
                acc[0][j][0] = fmaf(p0.x, wA[ky*3+0], fmaf(p0.y, wA[ky*3+1], fmaf(p1.x, wA[ky*3+2], acc[0][j][0])));
                acc[0][j][1] = fmaf(p0.y, wA[ky*3+0], fmaf(p1.x, wA[ky*3+1], fmaf(p1.y, wA[ky*3+2], acc[0][j][1])));
                acc[1][j][0] = fmaf(p0.x, wB[ky*3+0], fmaf(p0.y, wB[ky*3+1], fmaf(p1.x, wB[ky*3+2], acc[1][j][0])));
                acc[1][j][1] = fmaf(p0.y, wB[ky*3+0], fmaf(p1.x, wB[ky*3+1], fmaf(p1.y, wB[ky*3+2], acc[1][j][1])));
            }
        }

        if (c + 1 < C) K1_WRITE_STAGE((c + 1) & 1);
        __syncthreads();
    }

    #pragma unroll
    for (int j = 0; j < 2; ++j) {
        int hh = h0 + ty0 + j;
        float4 o;
        #pragma unroll
        for (int q = 0; q < 2; ++q) {
            int wwp = w0 + tx2 + q;
            float off0 = tanhf(acc[0][j][q]);
            float off1 = tanhf(acc[1][j][q]);
            float fx = (float)wwp + off0;
            float fy = (float)hh + off1;
            float gx = 2.0f * fx / (float)(W - 1) - 1.0f;
            float gy = 2.0f * fy / (float)(H - 1) - 1.0f;
            float ix = ((gx + 1.0f) * (float)W - 1.0f) * 0.5f;
            float iy = ((gy + 1.0f) * (float)H - 1.0f) * 0.5f;
            float ixr = reflect_coord(ix, W);
            float iyr = reflect_coord(iy, H);
            if (q == 0) { o.x = ixr; o.y = iyr; }
            else        { o.z = ixr; o.w = iyr; }
        }
        *(float4*)&ws[(size_t)b_ * HW + (size_t)hh * W + (w0 + tx2)] = o;
    }
}

// ---------------- sample + depthwise conv kernel (v4) ----------------
// Tap-window arithmetic: ix = (w+off)*W/(W-1) - 0.5, |drift| <= 1.503, so
// bilinear taps reach pixel +/- 2. With conv halo (hp in [h0-1, h0+16],
// wp in [w0-1, w0+64]) taps live in rows [h0-3, h0+18] (22 rows) and cols
// [w0-3, w0+66] (staged [w0-4, w0+68) for 16B alignment).
#define NC 8
#define K2_TW 64
#define K2_TH 16
#define XT_ROWS 22
#define XT_STRIDE 72
#define XT_N (XT_ROWS * XT_STRIDE)          // 1584 floats
#define XT_LOADS (XT_ROWS * 18)             // 396 float4 loads
#define XD_ROWS 18
#define XD_COLS 66
#define XD_STRIDE 68
#define META_N (XD_ROWS * XD_COLS)          // 1188

__global__ __launch_bounds__(256) void sample_dw_kernel(
        const float* __restrict__ x,
        const float2* __restrict__ ws,
        const float* __restrict__ dww,
        float* __restrict__ out) {
    __shared__ float xt[XT_N];
    __shared__ float xd[XD_ROWS * XD_STRIDE];
    __shared__ unsigned int m_addr[META_N];
    __shared__ float m_wx[META_N];
    __shared__ float m_wy[META_N];

    const int tid = threadIdx.x;
    const int bz = blockIdx.z;                 // b*(C/NC) + cg
    const int b_ = bz >> 2;
    const int c0 = (bz & 3) * NC;
    const int h0 = blockIdx.y * K2_TH;
    const int w0 = blockIdx.x * K2_TW;

    const float* xb = x + ((size_t)b_ * C + c0) * HW;
    const float2* wsb = ws + (size_t)b_ * HW;

    // prefetch channel 0 x-tile into regs
    float4 pf[2];
    #pragma unroll
    for (int k = 0; k < 2; ++k) {
        int idx = tid + k * 256;
        float4 v = {0.f, 0.f, 0.f, 0.f};
        if (idx < XT_LOADS) {
            int row = idx / 18, k4 = idx % 18;
            int grow = min(max(h0 - 3 + row, 0), H - 1);
            int gcol = min(max(w0 - 4 + k4 * 4, 0), W - 4);
            v = *(const float4*)(xb + grow * W + gcol);
        }
        pf[k] = v;
    }

    // Phase A: per-pixel meta, shared across channels
    const int addr_base = (h0 - 3) * XT_STRIDE + (w0 - 4);
    #pragma unroll
    for (int k = 0; k < 5; ++k) {
        int i = tid + k * 256;
        if (i < META_N) {
            int r = i / XD_COLS, q = i - r * XD_COLS;
            int hp = h0 - 1 + r, wp = w0 - 1 + q;
            unsigned int addr = 0xFFFFFFFFu;
            float wx1 = 0.f, wy1 = 0.f;
            if (hp >= 0 && hp < H && wp >= 0 && wp < W) {
                float2 crd = wsb[hp * W + wp];
                float ix0f = floorf(crd.x), iy0f = floorf(crd.y);
                wx1 = crd.x - ix0f; wy1 = crd.y - iy0f;
                int ix0 = min(max((int)ix0f, 0), W - 1);
                int iy0 = min(max((int)iy0f, 0), H - 1);
                addr = (unsigned int)(iy0 * XT_STRIDE + ix0 - addr_base);
            }
            m_addr[i] = addr;
            m_wx[i] = wx1;
            m_wy[i] = wy1;
        }
    }
    __syncthreads();

    for (int cc = 0; cc < NC; ++cc) {
        // write staged x-tile regs -> LDS
        #pragma unroll
        for (int k = 0; k < 2; ++k) {
            int idx = tid + k * 256;
            if (idx < XT_LOADS) {
                int row = idx / 18, k4 = idx % 18;
                *(float4*)&xt[row * XT_STRIDE + k4 * 4] = pf[k];
            }
        }
        __syncthreads();

        // prefetch next channel (hides under sample+conv)
        if (cc + 1 < NC) {
            const float* xc = xb + (size_t)(cc + 1) * HW;
            #pragma unroll
            for (int k = 0; k < 2; ++k) {
                int idx = tid + k * 256;
                float4 v = {0.f, 0.f, 0.f, 0.f};
                if (idx < XT_LOADS) {
                    int row = idx / 18, k4 = idx % 18;
                    int grow = min(max(h0 - 3 + row, 0), H - 1);
                    int gcol = min(max(w0 - 4 + k4 * 4, 0), W - 4);
                    v = *(const float4*)(xc + grow * W + gcol);
                }
                pf[k] = v;
            }
        }

        // sample from xt -> xd
        #pragma unroll
        for (int k = 0; k < 5; ++k) {
            int i = tid + k * 256;
            if (i < META_N) {
                int r = i / XD_COLS, q = i - r * XD_COLS;
                unsigned int addr = m_addr[i];
                float v = 0.0f;
                if (addr != 0xFFFFFFFFu) {
                    float wx1 = m_wx[i], wy1 = m_wy[i];
                    float wx0 = 1.0f - wx1, wy0 = 1.0f - wy1;
                    float v00 = xt[addr];
                    float v01 = xt[addr + 1];
                    float v10 = xt[addr + XT_STRIDE];
                    float v11 = xt[addr + XT_STRIDE + 1];
                    v = (v00 * wx0 + v01 * wx1) * wy0 + (v10 * wx0 + v11 * wx1) * wy1;
                }
                xd[r * XD_STRIDE + q] = v;
            }
        }

        // depthwise weights (wave-uniform -> scalar loads)
        float wk[9];
        const float* wc = dww + (size_t)(c0 + cc) * 9;
        #pragma unroll
        for (int i = 0; i < 9; ++i) wk[i] = wc[i];

        __syncthreads();

        // 3x3 depthwise conv from xd + ReLU; 2x2 outputs per thread
        const int tx2 = (tid & 31) * 2;
        const int ty0 = (tid >> 5) * 2;
        float a[2][2] = {{0.f, 0.f}, {0.f, 0.f}};
        #pragma unroll
        for (int r = 0; r < 4; ++r) {
            const float* rowp = xd + (ty0 + r) * XD_STRIDE + tx2;
            float2 p0 = *(const float2*)rowp;
            float2 p1 = *(const float2*)(rowp + 2);
            #pragma unroll
            for (int ky = 0; ky < 3; ++ky) {
                int j = r - ky;
                if (j < 0 || j > 1) continue;
                a[j][0] = fmaf(p0.x, wk[ky*3+0], fmaf(p0.y, wk[ky*3+1], fmaf(p1.x, wk[ky*3+2], a[j][0])));
                a[j][1] = fmaf(p0.y, wk[ky*3+0], fmaf(p1.x, wk[ky*3+1], fmaf(p1.y, wk[ky*3+2], a[j][1])));
            }
        }
        float* outc = out + ((size_t)b_ * C + c0 + cc) * HW;
        #pragma unroll
        for (int j = 0; j < 2; ++j) {
            float2 res;
            res.x = fmaxf(a[j][0], 0.0f);
            res.y = fmaxf(a[j][1], 0.0f);
            *(float2*)&outc[(size_t)(h0 + ty0 + j) * W + (w0 + tx2)] = res;
        }
        __syncthreads();
    }
}

extern "C" void kernel_launch(void* const* d_in, const int* in_sizes, int n_in,
                              void* d_out, int out_size, void* d_ws, size_t ws_size,
                              hipStream_t stream) {
    const float* x   = (const float*)d_in[0];
    const float* ow  = (const float*)d_in[1];
    const float* ob  = (const float*)d_in[2];
    const float* dww = (const float*)d_in[3];
    float* out = (float*)d_out;
    float2* ws = (float2*)d_ws;

    dim3 g1(W / K1_TW, H / K1_TH, B);
    offset_kernel<<<g1, 256, 0, stream>>>(x, ow, ob, ws);

    dim3 g2(W / K2_TW, H / K2_TH, B * (C / NC));
    sample_dw_kernel<<<g2, 256, 0, stream>>>(x, ws, dww, out);
}